// Round 11
// baseline (596.295 us; speedup 1.0000x reference)
//
#include <hip/hip_runtime.h>
#include <hip/hip_fp16.h>
#include <stdint.h>

#define NEG_ (-1e9f)

typedef _Float16 f16x8 __attribute__((ext_vector_type(8)));
typedef float    f32x4 __attribute__((ext_vector_type(4)));

__device__ __forceinline__ float fast_tanh(float x) {
  float e = __expf(2.0f * x);
  return (e - 1.0f) * __builtin_amdgcn_rcpf(e + 1.0f);
}

// ---------------------------------------------------------------------------
// K0: repack W [512 o][512 h] fp32 -> f16 in MFMA A-fragment stream order.
// seg = w*64 + ks*4 + io  (1KB each); w in 0..7 is the owning wave.
// lane i holds W[o = w*64+io*16+(i&15)][k = ks*32+(i>>4)*8 .. +8)
// ---------------------------------------------------------------------------
__global__ __launch_bounds__(256) void k0_cvt_w(const float* __restrict__ W,
                                                __half* __restrict__ Wws) {
  int g = blockIdx.x * 256 + threadIdx.x;   // 0..32767, one 16B chunk each
  int lane = g & 63;
  int seg  = g >> 6;                        // 0..511
  int io = seg & 3, ks = (seg >> 2) & 15, w = seg >> 6;   // w: 0..7
  int o = w * 64 + io * 16 + (lane & 15);
  int k = ks * 32 + (lane >> 4) * 8;
  const float2* src = (const float2*)(W + (size_t)o * 512 + k);
  __half2 h[4];
#pragma unroll
  for (int j = 0; j < 4; ++j) { float2 f = src[j]; h[j] = __floats2half2_rn(f.x, f.y); }
  uint4 u;
  u.x = *(uint32_t*)&h[0]; u.y = *(uint32_t*)&h[1];
  u.z = *(uint32_t*)&h[2]; u.w = *(uint32_t*)&h[3];
  *(uint4*)(Wws + (size_t)seg * 512 + (size_t)lane * 8) = u;
}

// ---------------------------------------------------------------------------
// K1 (round-10 design, resubmitted after infra failure): barrier-free main
// loop, NO X-LDS. Per 64-row tile mtile, the 16 ks-steps read A from
// L2-resident Wws and B DIRECTLY from global enc (fp32 -> f16 cvt in-loop).
// Every variant since round 0 had a memory-only staging phase
// barrier-separated from a memory-idle compute phase; co-resident blocks
// stay phase-locked, so no pipe ever exceeded ~25%. Here loads are
// interleaved 12:16 with MFMA through the whole kernel: continuous demand,
// no barriers until the epilogue, no staging registers to spill, LDS down
// to 18.5 KB. X is re-read 8x from L2 (~1 MB/block; L2 ceiling ~97 us
// chip-wide) while HBM sees only the compulsory 256 MB. psum re-reads X
// from L2 (hot).
// ---------------------------------------------------------------------------
__global__ __launch_bounds__(512, 4) void k1_scores(
    const float* __restrict__ enc, const int* __restrict__ msk,
    const float* __restrict__ bias, const float* __restrict__ ctx,
    const __half* __restrict__ Wws, float* __restrict__ scores,
    float* __restrict__ psum, float* __restrict__ mpart,
    float* __restrict__ lpart) {
  __shared__ float sred[512];
  __shared__ float pbuf[64];
  __shared__ __align__(16) float pred[8 * 512];   // 16 KB

  const int t = threadIdx.x;
  const int w = t >> 6;          // 0..7: o-chunk this wave owns
  const int lane = t & 63;
  const int quad = lane >> 4;
  const int l15 = lane & 15;
  const size_t mtile = blockIdx.x;
  const float* Xb = enc + mtile * (size_t)(64 * 512);

  f32x4 acc[4][4];
#pragma unroll
  for (int io = 0; io < 4; ++io)
#pragma unroll
    for (int is = 0; is < 4; ++is) acc[io][is] = (f32x4){0.f, 0.f, 0.f, 0.f};

  // ---- barrier-free main loop: A from Wws (L2), B from enc (L2/HBM) ----
#pragma unroll 2
  for (int ks = 0; ks < 16; ++ks) {
    f16x8 af[4];
    {
      const f16x8* sp = (const f16x8*)(Wws +
          ((size_t)(w * 64 + ks * 4) * 512) + (size_t)lane * 8);
#pragma unroll
      for (int io = 0; io < 4; ++io) af[io] = sp[io * 64];
    }
#pragma unroll
    for (int is = 0; is < 4; ++is) {
      int s = is * 16 + l15;
      const float* bp = Xb + (size_t)s * 512 + ks * 32 + quad * 8;
      f32x4 xa = *(const f32x4*)bp;
      f32x4 xb = *(const f32x4*)(bp + 4);
      f16x8 bf;
      bf[0] = (_Float16)xa[0]; bf[1] = (_Float16)xa[1];
      bf[2] = (_Float16)xa[2]; bf[3] = (_Float16)xa[3];
      bf[4] = (_Float16)xb[0]; bf[5] = (_Float16)xb[1];
      bf[6] = (_Float16)xb[2]; bf[7] = (_Float16)xb[3];
#pragma unroll
      for (int io = 0; io < 4; ++io)
        acc[io][is] = __builtin_amdgcn_mfma_f32_16x16x32_f16(af[io], bf, acc[io][is], 0, 0, 0);
    }
  }

  // ---- epilogue: fold tanh(acc + b) * v into per-row partial scores ----
  float ps[4] = {0.f, 0.f, 0.f, 0.f};
#pragma unroll
  for (int io = 0; io < 4; ++io) {
    int ob = w * 64 + io * 16 + quad * 4;   // C row m = quad*4 + reg
    float4 b4 = *(const float4*)(bias + ob);
    float4 v4 = *(const float4*)(ctx + ob);
#pragma unroll
    for (int is = 0; is < 4; ++is) {
      const f32x4 a = acc[io][is];
      ps[is] += fast_tanh(a[0] + b4.x) * v4.x + fast_tanh(a[1] + b4.y) * v4.y +
                fast_tanh(a[2] + b4.z) * v4.z + fast_tanh(a[3] + b4.w) * v4.w;
    }
  }
#pragma unroll
  for (int is = 0; is < 4; ++is) {   // sum over this wave's 64 o's
    ps[is] += __shfl_xor(ps[is], 16, 64);
    ps[is] += __shfl_xor(ps[is], 32, 64);
  }

  if (lane < 16) {
#pragma unroll
    for (int is = 0; is < 4; ++is) sred[w * 64 + is * 16 + lane] = ps[is];
  }
  __syncthreads();
  if (t < 64) {   // wave 0: finalize scores + local softmax stats
    float sc = 0.f;
#pragma unroll
    for (int k = 0; k < 8; ++k) sc += sred[k * 64 + t];
    size_t row = mtile * 64 + t;
    float sm = msk[row] ? sc : NEG_;
    scores[row] = sm;                       // raw masked score for combine pass
    float m = sm;
#pragma unroll
    for (int off = 32; off >= 1; off >>= 1) m = fmaxf(m, __shfl_xor(m, off, 64));
    float p = __expf(sm - m);
    float l = p;
#pragma unroll
    for (int off = 32; off >= 1; off >>= 1) l += __shfl_xor(l, off, 64);
    pbuf[t] = p;
    if (t == 0) { mpart[mtile] = m; lpart[mtile] = l; }
  }
  __syncthreads();

  // ---- psum partial: re-read X rows from global (L2-hot).
  //      wave w covers s = w*8..w*8+7; lane covers h = lane*8..lane*8+7 ----
  float pacc[8] = {0.f, 0.f, 0.f, 0.f, 0.f, 0.f, 0.f, 0.f};
#pragma unroll
  for (int si = 0; si < 8; ++si) {
    int s = (w << 3) + si;
    float pv = pbuf[s];
    const float* xp = Xb + (size_t)s * 512 + lane * 8;
    f32x4 xa = *(const f32x4*)xp;
    f32x4 xb = *(const f32x4*)(xp + 4);
    pacc[0] = fmaf(pv, xa[0], pacc[0]);
    pacc[1] = fmaf(pv, xa[1], pacc[1]);
    pacc[2] = fmaf(pv, xa[2], pacc[2]);
    pacc[3] = fmaf(pv, xa[3], pacc[3]);
    pacc[4] = fmaf(pv, xb[0], pacc[4]);
    pacc[5] = fmaf(pv, xb[1], pacc[5]);
    pacc[6] = fmaf(pv, xb[2], pacc[6]);
    pacc[7] = fmaf(pv, xb[3], pacc[7]);
  }
  {
    float4 lo = {pacc[0], pacc[1], pacc[2], pacc[3]};
    float4 hi = {pacc[4], pacc[5], pacc[6], pacc[7]};
    *(float4*)&pred[w * 512 + lane * 4] = lo;       // conflict-free b128 stores
    *(float4*)&pred[w * 512 + 256 + lane * 4] = hi;
  }
  __syncthreads();
  if (t < 128) {                    // h float4-group g = t
    int half = t & 1, c2 = t >> 1;
    float4 a = {0.f, 0.f, 0.f, 0.f};
#pragma unroll
    for (int w2 = 0; w2 < 8; ++w2) {
      float4 pv = *(const float4*)&pred[w2 * 512 + half * 256 + c2 * 4];
      a.x += pv.x; a.y += pv.y; a.z += pv.z; a.w += pv.w;
    }
    *(float4*)&psum[mtile * 512 + (size_t)t * 4] = a;
  }
}

// ---------------------------------------------------------------------------
// K2 (combine, 512 blocks): block (b,g) recomputes M,Z redundantly from the
// tiny mpart/lpart arrays (L2-hot), rewrites the attn slice
// s in [g*256, g*256+256), and reduces the psum h-slice [g*64, g*64+64).
// ---------------------------------------------------------------------------
__global__ __launch_bounds__(256) void k2_combine(
    float* __restrict__ attn, const float* __restrict__ psum,
    const float* __restrict__ mpart, const float* __restrict__ lpart,
    float* __restrict__ out0) {
  const int b = blockIdx.x >> 3, g = blockIdx.x & 7, t = threadIdx.x;
  __shared__ float ml[32], ll[32];
  if (t < 32) { ml[t] = mpart[b * 32 + t]; ll[t] = lpart[b * 32 + t]; }
  __syncthreads();
  float M = -3.4e38f;
#pragma unroll
  for (int i = 0; i < 32; ++i) M = fmaxf(M, ml[i]);
  float Z = 0.f;
#pragma unroll
  for (int i = 0; i < 32; ++i) Z += __expf(ml[i] - M) * ll[i];
  float invZ = 1.0f / Z;

  // attn rewrite: one element per thread
  {
    int s = g * 256 + t;
    float* row = attn + (size_t)b * 2048;
    row[s] = __expf(row[s] - M) * invZ;
  }

  // psum reduce: 64 threads cover h = g*64 .. g*64+63
  if (t < 64) {
    int h = g * 64 + t;
    float a = 0.f;
#pragma unroll
    for (int c2 = 0; c2 < 32; ++c2) {
      float wv = __expf(ml[c2] - M);
      a = fmaf(wv, psum[((size_t)(b * 32 + c2)) * 512 + h], a);
    }
    out0[(size_t)b * 512 + h] = a * invZ;
  }
}

// ---------------------------------------------------------------------------
extern "C" void kernel_launch(void* const* d_in, const int* in_sizes, int n_in,
                              void* d_out, int out_size, void* d_ws, size_t ws_size,
                              hipStream_t stream) {
  (void)in_sizes; (void)n_in; (void)out_size; (void)ws_size;
  const float* enc  = (const float*)d_in[0];  // [64,2048,512] fp32
  const int*   msk  = (const int*)d_in[1];    // [64,2048] bool->int32
  const float* W    = (const float*)d_in[2];  // [512,512] fp32
  const float* bias = (const float*)d_in[3];  // [512] fp32
  const float* ctx  = (const float*)d_in[4];  // [512] fp32
  float* out0 = (float*)d_out;                // [64,512] weighted output
  float* attn = out0 + 64 * 512;              // [64,2048] scores -> attn (in place)

  __half* Wws  = (__half*)d_ws;                               // 512 KB
  float*  psum = (float*)((char*)d_ws + (512u << 10));        // 4 MB  [2048][512]
  float*  mprt = psum + (size_t)2048 * 512;                   // 8 KB
  float*  lprt = mprt + 2048;                                 // 8 KB

  k0_cvt_w<<<128, 256, 0, stream>>>(W, Wws);
  k1_scores<<<2048, 512, 0, stream>>>(enc, msk, bias, ctx, Wws, attn,
                                      psum, mprt, lprt);
  k2_combine<<<512, 256, 0, stream>>>(attn, psum, mprt, lprt, out0);
}

// Round 12
// 448.380 us; speedup vs baseline: 1.3299x; 1.3299x over previous
//
#include <hip/hip_runtime.h>
#include <hip/hip_fp16.h>
#include <stdint.h>

#define NEG_ (-1e9f)
#define LROW 516   // padded LDS row stride in f32 (516%32==4 -> 2-way reads, free)

typedef _Float16 f16x8 __attribute__((ext_vector_type(8)));
typedef float    f32x4 __attribute__((ext_vector_type(4)));

__device__ __forceinline__ float fast_tanh(float x) {
  float e = __expf(2.0f * x);
  return (e - 1.0f) * __builtin_amdgcn_rcpf(e + 1.0f);
}

// ---------------------------------------------------------------------------
// K0: repack W [512 o][512 h] fp32 -> f16 in MFMA A-fragment stream order.
// seg = w*64 + ks*4 + io  (1KB each); w in 0..7 is the owning wave.
// lane i holds W[o = w*64+io*16+(i&15)][k = ks*32+(i>>4)*8 .. +8)
// ---------------------------------------------------------------------------
__global__ __launch_bounds__(256) void k0_cvt_w(const float* __restrict__ W,
                                                __half* __restrict__ Wws) {
  int g = blockIdx.x * 256 + threadIdx.x;   // 0..32767, one 16B chunk each
  int lane = g & 63;
  int seg  = g >> 6;                        // 0..511
  int io = seg & 3, ks = (seg >> 2) & 15, w = seg >> 6;   // w: 0..7
  int o = w * 64 + io * 16 + (lane & 15);
  int k = ks * 32 + (lane >> 4) * 8;
  const float2* src = (const float2*)(W + (size_t)o * 512 + k);
  __half2 h[4];
#pragma unroll
  for (int j = 0; j < 4; ++j) { float2 f = src[j]; h[j] = __floats2half2_rn(f.x, f.y); }
  uint4 u;
  u.x = *(uint32_t*)&h[0]; u.y = *(uint32_t*)&h[1];
  u.z = *(uint32_t*)&h[2]; u.w = *(uint32_t*)&h[3];
  *(uint4*)(Wws + (size_t)seg * 512 + (size_t)lane * 8) = u;
}

// ---------------------------------------------------------------------------
// K1 (round-12): coalesced DMA staging, padded fp32 tile, no register
// staging at all. Evidence chain: register staging always spilled (rounds
// 2-9, WRITE 110-640 MB); direct-global compute was latency-bound (round
// 11: clean traffic, 9.6% BW); round 7's DMA over-fetched 3.4x because its
// per-lane source addresses were XOR-scattered. Here global_load_lds reads
// strictly linear 1KB/instruction (lane*16B within a contiguous chunk, 2
// chunks per 2KB row) -> full coalescing, zero registers, 128 KB/CU in
// flight >> the ~10 KB latency-BW product -> staging at full BW share.
// Bank conflicts are killed by row PADDING (stride 516 f32: the 16 lanes
// reading distinct rows at one column land 2 lanes/bank = free), which
// unlike XOR-swizzle does not perturb the global access pattern.
// fp32->f16 for B happens at fragment build (VALU, overlaps MFMA).
// LDS 147 KB -> 1 block/CU; launch_bounds(512,2) -> 256-reg budget, ~174
// live, no spill.
// ---------------------------------------------------------------------------
__global__ __launch_bounds__(512, 2) void k1_scores(
    const float* __restrict__ enc, const int* __restrict__ msk,
    const float* __restrict__ bias, const float* __restrict__ ctx,
    const __half* __restrict__ Wws, float* __restrict__ scores,
    float* __restrict__ psum, float* __restrict__ mpart,
    float* __restrict__ lpart) {
  __shared__ __align__(16) float Xl[64 * LROW];   // 129 KB padded fp32 tile
  __shared__ float sred[512];
  __shared__ float pbuf[64];
  __shared__ __align__(16) float pred[8 * 512];   // 16 KB

  const int t = threadIdx.x;
  const int w = t >> 6;          // 0..7: o-chunk this wave owns
  const int lane = t & 63;
  const int quad = lane >> 4;
  const int l15 = lane & 15;
  const size_t mtile = blockIdx.x;
  const float* Xg = enc + mtile * (size_t)(64 * 512);

  // ---- stage: 16 global_load_lds(16B) per thread, linear source ----
  // instruction (w, it) covers seg = it*8+w: row s = seg>>1, half q = seg&1.
  // src: 1KB contiguous (lane*16B); dst: wave-uniform base in padded row.
  {
#pragma unroll
    for (int it = 0; it < 16; ++it) {
      int seg = it * 8 + w;          // 0..127
      int s = seg >> 1, q = seg & 1;
      const float* src = Xg + (size_t)s * 512 + q * 256 + lane * 4;
      float* dst = &Xl[s * LROW + q * 256];
      __builtin_amdgcn_global_load_lds(
          (const __attribute__((address_space(1))) void*)src,
          (__attribute__((address_space(3))) void*)dst, 16, 0, 0);
    }
  }

  // A-fragment register ring, depth-2 prefetch from L2-resident Wws
  f16x8 abuf[3][4];
  auto aload = [&](int slot, int ks) {
    const f16x8* sp = (const f16x8*)(Wws +
        ((size_t)(w * 64 + ks * 4) * 512) + (size_t)lane * 8);
#pragma unroll
    for (int io = 0; io < 4; ++io) abuf[slot][io] = sp[io * 64];
  };
  aload(0, 0);
  aload(1, 1);

  __syncthreads();   // drains vmcnt(0): DMA tile + A slots 0/1 resident

  f32x4 acc[4][4];
#pragma unroll
  for (int io = 0; io < 4; ++io)
#pragma unroll
    for (int is = 0; is < 4; ++is) acc[io][is] = (f32x4){0.f, 0.f, 0.f, 0.f};

#pragma unroll
  for (int ks = 0; ks < 16; ++ks) {
    if (ks + 2 < 16) aload((ks + 2) % 3, ks + 2);  // prefetch ahead
    const f16x8* acur = abuf[ks % 3];
#pragma unroll
    for (int is = 0; is < 4; ++is) {
      int s = is * 16 + l15;
      const float* bp = &Xl[s * LROW + ks * 32 + quad * 8];
      f32x4 xa = *(const f32x4*)bp;
      f32x4 xb = *(const f32x4*)(bp + 4);
      f16x8 bf;
      bf[0] = (_Float16)xa[0]; bf[1] = (_Float16)xa[1];
      bf[2] = (_Float16)xa[2]; bf[3] = (_Float16)xa[3];
      bf[4] = (_Float16)xb[0]; bf[5] = (_Float16)xb[1];
      bf[6] = (_Float16)xb[2]; bf[7] = (_Float16)xb[3];
#pragma unroll
      for (int io = 0; io < 4; ++io)
        acc[io][is] = __builtin_amdgcn_mfma_f32_16x16x32_f16(acur[io], bf, acc[io][is], 0, 0, 0);
    }
  }

  // ---- epilogue: fold tanh(acc + b) * v into per-row partial scores ----
  float ps[4] = {0.f, 0.f, 0.f, 0.f};
#pragma unroll
  for (int io = 0; io < 4; ++io) {
    int ob = w * 64 + io * 16 + quad * 4;   // C row m = quad*4 + reg
    float4 b4 = *(const float4*)(bias + ob);
    float4 v4 = *(const float4*)(ctx + ob);
#pragma unroll
    for (int is = 0; is < 4; ++is) {
      const f32x4 a = acc[io][is];
      ps[is] += fast_tanh(a[0] + b4.x) * v4.x + fast_tanh(a[1] + b4.y) * v4.y +
                fast_tanh(a[2] + b4.z) * v4.z + fast_tanh(a[3] + b4.w) * v4.w;
    }
  }
#pragma unroll
  for (int is = 0; is < 4; ++is) {   // sum over this wave's 64 o's
    ps[is] += __shfl_xor(ps[is], 16, 64);
    ps[is] += __shfl_xor(ps[is], 32, 64);
  }

  if (lane < 16) {
#pragma unroll
    for (int is = 0; is < 4; ++is) sred[w * 64 + is * 16 + lane] = ps[is];
  }
  __syncthreads();
  if (t < 64) {   // wave 0: finalize scores + local softmax stats
    float sc = 0.f;
#pragma unroll
    for (int k = 0; k < 8; ++k) sc += sred[k * 64 + t];
    size_t row = mtile * 64 + t;
    float sm = msk[row] ? sc : NEG_;
    scores[row] = sm;                       // raw masked score for combine pass
    float m = sm;
#pragma unroll
    for (int off = 32; off >= 1; off >>= 1) m = fmaxf(m, __shfl_xor(m, off, 64));
    float p = __expf(sm - m);
    float l = p;
#pragma unroll
    for (int off = 32; off >= 1; off >>= 1) l += __shfl_xor(l, off, 64);
    pbuf[t] = p;
    if (t == 0) { mpart[mtile] = m; lpart[mtile] = l; }
  }
  __syncthreads();

  // ---- psum partial from the resident padded tile:
  //      wave w covers s = w*8..w*8+7; lane covers h = lane*8..lane*8+7 ----
  float pacc[8] = {0.f, 0.f, 0.f, 0.f, 0.f, 0.f, 0.f, 0.f};
#pragma unroll
  for (int si = 0; si < 8; ++si) {
    int s = (w << 3) + si;
    float pv = pbuf[s];
    const float* xp = &Xl[s * LROW + lane * 8];
    f32x4 xa = *(const f32x4*)xp;
    f32x4 xb = *(const f32x4*)(xp + 4);
    pacc[0] = fmaf(pv, xa[0], pacc[0]);
    pacc[1] = fmaf(pv, xa[1], pacc[1]);
    pacc[2] = fmaf(pv, xa[2], pacc[2]);
    pacc[3] = fmaf(pv, xa[3], pacc[3]);
    pacc[4] = fmaf(pv, xb[0], pacc[4]);
    pacc[5] = fmaf(pv, xb[1], pacc[5]);
    pacc[6] = fmaf(pv, xb[2], pacc[6]);
    pacc[7] = fmaf(pv, xb[3], pacc[7]);
  }
  {
    float4 lo = {pacc[0], pacc[1], pacc[2], pacc[3]};
    float4 hi = {pacc[4], pacc[5], pacc[6], pacc[7]};
    *(float4*)&pred[w * 512 + lane * 4] = lo;       // conflict-free b128 stores
    *(float4*)&pred[w * 512 + 256 + lane * 4] = hi;
  }
  __syncthreads();
  if (t < 128) {                    // h float4-group g = t
    int half = t & 1, c2 = t >> 1;
    float4 a = {0.f, 0.f, 0.f, 0.f};
#pragma unroll
    for (int w2 = 0; w2 < 8; ++w2) {
      float4 pv = *(const float4*)&pred[w2 * 512 + half * 256 + c2 * 4];
      a.x += pv.x; a.y += pv.y; a.z += pv.z; a.w += pv.w;
    }
    *(float4*)&psum[mtile * 512 + (size_t)t * 4] = a;
  }
}

// ---------------------------------------------------------------------------
// K2 (combine, 512 blocks): block (b,g) recomputes M,Z redundantly from the
// tiny mpart/lpart arrays (L2-hot), rewrites the attn slice
// s in [g*256, g*256+256), and reduces the psum h-slice [g*64, g*64+64).
// ---------------------------------------------------------------------------
__global__ __launch_bounds__(256) void k2_combine(
    float* __restrict__ attn, const float* __restrict__ psum,
    const float* __restrict__ mpart, const float* __restrict__ lpart,
    float* __restrict__ out0) {
  const int b = blockIdx.x >> 3, g = blockIdx.x & 7, t = threadIdx.x;
  __shared__ float ml[32], ll[32];
  if (t < 32) { ml[t] = mpart[b * 32 + t]; ll[t] = lpart[b * 32 + t]; }
  __syncthreads();
  float M = -3.4e38f;
#pragma unroll
  for (int i = 0; i < 32; ++i) M = fmaxf(M, ml[i]);
  float Z = 0.f;
#pragma unroll
  for (int i = 0; i < 32; ++i) Z += __expf(ml[i] - M) * ll[i];
  float invZ = 1.0f / Z;

  // attn rewrite: one element per thread
  {
    int s = g * 256 + t;
    float* row = attn + (size_t)b * 2048;
    row[s] = __expf(row[s] - M) * invZ;
  }

  // psum reduce: 64 threads cover h = g*64 .. g*64+63
  if (t < 64) {
    int h = g * 64 + t;
    float a = 0.f;
#pragma unroll
    for (int c2 = 0; c2 < 32; ++c2) {
      float wv = __expf(ml[c2] - M);
      a = fmaf(wv, psum[((size_t)(b * 32 + c2)) * 512 + h], a);
    }
    out0[(size_t)b * 512 + h] = a * invZ;
  }
}

// ---------------------------------------------------------------------------
extern "C" void kernel_launch(void* const* d_in, const int* in_sizes, int n_in,
                              void* d_out, int out_size, void* d_ws, size_t ws_size,
                              hipStream_t stream) {
  (void)in_sizes; (void)n_in; (void)out_size; (void)ws_size;
  const float* enc  = (const float*)d_in[0];  // [64,2048,512] fp32
  const int*   msk  = (const int*)d_in[1];    // [64,2048] bool->int32
  const float* W    = (const float*)d_in[2];  // [512,512] fp32
  const float* bias = (const float*)d_in[3];  // [512] fp32
  const float* ctx  = (const float*)d_in[4];  // [512] fp32
  float* out0 = (float*)d_out;                // [64,512] weighted output
  float* attn = out0 + 64 * 512;              // [64,2048] scores -> attn (in place)

  __half* Wws  = (__half*)d_ws;                               // 512 KB
  float*  psum = (float*)((char*)d_ws + (512u << 10));        // 4 MB  [2048][512]
  float*  mprt = psum + (size_t)2048 * 512;                   // 8 KB
  float*  lprt = mprt + 2048;                                 // 8 KB

  k0_cvt_w<<<128, 256, 0, stream>>>(W, Wws);
  k1_scores<<<2048, 512, 0, stream>>>(enc, msk, bias, ctx, Wws, attn,
                                      psum, mprt, lprt);
  k2_combine<<<512, 256, 0, stream>>>(attn, psum, mprt, lprt, out0);
}